// Round 8
// baseline (395.305 us; speedup 1.0000x reference)
//
#include <hip/hip_runtime.h>
#include <hip/hip_bf16.h>
#include <stdint.h>

// ---------------------------------------------------------------------------
// STE ternary linear: out = x @ q^T, q = ternary(weight, thr=0.05*mean|w|)
// x: [8192, 4096] fp32, weight: [4096, 4096] fp32, out: [8192, 4096] fp32
//
// R1 bf16 m97: 316us. R4 i8 m97: 165us (37.5%). R5 i8 8-phase 256^2: 144us
//     (41%). R8 i8 1-barrier: 136.6us (45%, VGPR 124, no spill, conflicts 0).
// Model: all three stuck at 5100-5400 cyc/tile vs 2610 MFMA floor. ~2500 cyc
//     invariant overhead across opposite sync structures. R8 suspect: compiler
//     sinks gld_lds to just before tile-end vmcnt(0) -> full memory latency
//     exposed per tile. i8 also halves MFMA work per barrier vs bf16 m201.
// R9: BK=64, TRIPLE-buffered 16KB tile bufs (96KB LDS), stage t+2 during t,
//     tile-end vmcnt(4) retires t+1's loads (issued a full tile earlier).
//     Sink-robust: counted wait never touches just-issued loads. 1 barrier
//     per tile, 32 RAW-independent MFMAs/cluster, no asm lgkm, setprio.
//     64B-row swizzle: slot ^= (r&3)^((r>>2)&3) (R7 family, algebraically
//     re-verified; R7 failed on registers not layout).
//     Predicted: gemm ~85-105us, MfmaUtil 60-75%, conflicts ~0, VGPR ~110.
// ---------------------------------------------------------------------------

typedef __attribute__((ext_vector_type(4))) int i32x4;

#define KDIM 4096
#define NDIM 4096

#define M_ROWS 8192     // x rows (blocks 0..M_ROWS-1 in prep)
#define ABS_BLOCKS 1024 // w abs-mean blocks

__device__ inline void gld_lds16(const void* g, void* l) {
  // 16B per lane, LDS dest = wave-uniform base + lane*16
  __builtin_amdgcn_global_load_lds(
      (__attribute__((address_space(1))) void*)g,
      (__attribute__((address_space(3))) void*)l,
      16, 0, 0);
}

__device__ inline int pack4(int a, int b, int c, int d) {
  return (a & 255) | ((b & 255) << 8) | ((c & 255) << 16) | (d << 24);
}

__device__ inline int q8(float v, float inv) {
  int q = __float2int_rn(v * inv);
  return q > 127 ? 127 : (q < -127 ? -127 : q);
}

// ---------------- fused prep: per-row x quant || w abs-mean -----------------
__global__ __launch_bounds__(256) void prep_kernel(
    const float4* __restrict__ x, signed char* __restrict__ xq,
    float* __restrict__ steps, const float4* __restrict__ w, int wn4,
    double* __restrict__ sum) {
  if (blockIdx.x < M_ROWS) {
    const int row = blockIdx.x;
    const float4* xr = x + (size_t)row * 1024;  // 4096 floats = 1024 float4
    float4 v[4];
    float amax = 0.0f;
#pragma unroll
    for (int j = 0; j < 4; ++j) {
      v[j] = xr[threadIdx.x + 256 * j];
      amax = fmaxf(amax, fmaxf(fmaxf(fabsf(v[j].x), fabsf(v[j].y)),
                               fmaxf(fabsf(v[j].z), fabsf(v[j].w))));
    }
#pragma unroll
    for (int off = 32; off > 0; off >>= 1)
      amax = fmaxf(amax, __shfl_down(amax, off, 64));
    __shared__ float wmax[4];
    const int lane = threadIdx.x & 63, wave = threadIdx.x >> 6;
    if (lane == 0) wmax[wave] = amax;
    __syncthreads();
    const float m = fmaxf(fmaxf(wmax[0], wmax[1]), fmaxf(wmax[2], wmax[3]));
    const float inv = m > 0.0f ? 127.0f / m : 0.0f;
    if (threadIdx.x == 0) steps[row] = m > 0.0f ? m / 127.0f : 0.0f;
    int* out = (int*)(xq + (size_t)row * 4096);
#pragma unroll
    for (int j = 0; j < 4; ++j) {
      out[threadIdx.x + 256 * j] = pack4(q8(v[j].x, inv), q8(v[j].y, inv),
                                         q8(v[j].z, inv), q8(v[j].w, inv));
    }
  } else {
    double s = 0.0;
    const int stride = ABS_BLOCKS * 256;
    for (int i = (blockIdx.x - M_ROWS) * 256 + threadIdx.x; i < wn4;
         i += stride) {
      float4 v = w[i];
      s += (double)((fabsf(v.x) + fabsf(v.y)) + (fabsf(v.z) + fabsf(v.w)));
    }
#pragma unroll
    for (int off = 32; off > 0; off >>= 1) s += __shfl_down(s, off, 64);
    __shared__ double wsum[4];
    const int lane = threadIdx.x & 63, wave = threadIdx.x >> 6;
    if (lane == 0) wsum[wave] = s;
    __syncthreads();
    if (threadIdx.x == 0) atomicAdd(sum, wsum[0] + wsum[1] + wsum[2] + wsum[3]);
  }
}

// ---------------- ternary quantize weight -> i8 {-1,0,+1} -------------------
__global__ __launch_bounds__(256) void quant_kernel(
    const float4* __restrict__ w, const double* __restrict__ sum,
    int* __restrict__ q, int n4, double inv_n) {
  const float thr = (float)(0.05 * (*sum) * inv_n);
  const int stride = gridDim.x * blockDim.x;
  for (int i = blockIdx.x * blockDim.x + threadIdx.x; i < n4; i += stride) {
    float4 v = w[i];
    int a = v.x > thr ? 1 : (v.x < -thr ? -1 : 0);
    int b = v.y > thr ? 1 : (v.y < -thr ? -1 : 0);
    int c = v.z > thr ? 1 : (v.z < -thr ? -1 : 0);
    int d = v.w > thr ? 1 : (v.w < -thr ? -1 : 0);
    q[i] = pack4(a, b, c, d);
  }
}

// ---------------- i8 GEMM, 256^2, BK=64, triple-buffer, stage t+2 -----------
// A: [M][4096] i8, B: [4096][4096] i8 (row = out col), C = i32acc * steps[m]
// 512 thr = 8 waves (2M x 4N); per-wave out 128x64 = acc[8][4] i32x4.
// LDS: A 3x16K @0, B 3x16K @49152 (96 KiB). Tile t reads buf[t%3]; stages
// tile t+2 into buf[(t+2)%3]; tile-end vmcnt(4) retires t+1's 4 loads
// (issued one full tile ago -> latency fully hidden, sink-robust).
// 64B-row swizzle: LDS(r, slot s) holds global slot s^f(r), f(r)=(r&3)^
// ((r>>2)&3). Write: lane l -> row l>>2, slot l&3, source pre-swizzled.
// Read: lane reads row fr=lane&15 at slot (lane>>4)^f(fr) -> recovers
// global slot lane>>4. Even/odd row classes spread 2-deep per bank: free.
// Per tile: 12 ds_read_b128 (8 A + 4 B), 4 gld_lds, 32 independent MFMA,
// vmcnt(4), barrier, sched_barrier(0). Tail: t=62 vmcnt(0); t=63 bare.
#define MFMA_I8 __builtin_amdgcn_mfma_i32_16x16x64_i8

#define TILE_BODY(T, BR, BS, STAGE, VMN)                                    \
  {                                                                         \
    const unsigned char* Ab = ldsA + (BR) * 16384;                          \
    const unsigned char* Bb = ldsB + (BR) * 16384;                          \
    i32x4 af[8], bf[4];                                                     \
    _Pragma("unroll") for (int ni = 0; ni < 4; ++ni)                        \
        bf[ni] = *(const i32x4*)(Bb + bro + ni * 1024);                     \
    _Pragma("unroll") for (int m = 0; m < 8; ++m)                           \
        af[m] = *(const i32x4*)(Ab + aro + m * 1024);                       \
    if (STAGE) {                                                            \
      const size_t ko = (size_t)((T) + 2) * 64;                             \
      gld_lds16(aG0 + ko, ldsA + (BS) * 16384 + sd0);                       \
      gld_lds16(aG1 + ko, ldsA + (BS) * 16384 + sd1);                       \
      gld_lds16(bG0 + ko, ldsB + (BS) * 16384 + sd0);                       \
      gld_lds16(bG1 + ko, ldsB + (BS) * 16384 + sd1);                       \
    }                                                                       \
    __builtin_amdgcn_s_setprio(1);                                          \
    _Pragma("unroll") for (int m = 0; m < 8; ++m)                           \
      _Pragma("unroll") for (int ni = 0; ni < 4; ++ni)                      \
          acc[m][ni] = MFMA_I8(af[m], bf[ni], acc[m][ni], 0, 0, 0);         \
    __builtin_amdgcn_s_setprio(0);                                          \
    asm volatile("s_waitcnt vmcnt(" #VMN ")" ::: "memory");                 \
    __builtin_amdgcn_s_barrier();                                           \
    __builtin_amdgcn_sched_barrier(0);                                      \
  }

__global__ __launch_bounds__(512, 2) void gemm_i8_3buf(
    const signed char* __restrict__ A, const signed char* __restrict__ B,
    const float* __restrict__ steps, float* __restrict__ C) {
  __shared__ unsigned char lds[98304];  // A 3x16K @0, B 3x16K @49152

  const int tid = threadIdx.x;
  const int lane = tid & 63;
  const int w = tid >> 6;

  const int bm = blockIdx.y * 256;
  const int bn = blockIdx.x * 256;

  // ---- staging: wave w stages chunks 2w, 2w+1 (16 rows x 64B = 1KB each) ---
  const int rl4 = lane >> 2;  // row within chunk (4 lanes/row)
  const int csw = (((lane & 3) ^ ((lane >> 2) & 3) ^ ((lane >> 4) & 3)) << 4);
  const signed char* aG0 = A + (size_t)(bm + 32 * w + rl4) * KDIM + csw;
  const signed char* aG1 = aG0 + (size_t)16 * KDIM;
  const signed char* bG0 = B + (size_t)(bn + 32 * w + rl4) * KDIM + csw;
  const signed char* bG1 = bG0 + (size_t)16 * KDIM;
  unsigned char* const ldsA = lds;
  unsigned char* const ldsB = lds + 49152;
  const int sd0 = 2 * w * 1024;  // chunk 2w LDS offset (+lane*16 implicit)
  const int sd1 = sd0 + 1024;

  // ---- fragment read addressing ----
  const int fr = lane & 15;
  const int cc = (((lane >> 4) ^ (lane & 3) ^ ((lane >> 2) & 3)) << 4);
  const int wm = (w >> 2) * 128;
  const int wn = (w & 3) * 64;
  const int aro = (wm + fr) * 64 + cc;
  const int bro = (wn + fr) * 64 + cc;

  i32x4 acc[8][4] = {};

  // ---- prologue: stage T0 -> buf0 (4 loads), T1 -> buf1 (4 loads) ----
  gld_lds16(aG0, ldsA + sd0);
  gld_lds16(aG1, ldsA + sd1);
  gld_lds16(bG0, ldsB + sd0);
  gld_lds16(bG1, ldsB + sd1);
  gld_lds16(aG0 + 64, ldsA + 16384 + sd0);
  gld_lds16(aG1 + 64, ldsA + 16384 + sd1);
  gld_lds16(bG0 + 64, ldsB + 16384 + sd0);
  gld_lds16(bG1 + 64, ldsB + 16384 + sd1);
  asm volatile("s_waitcnt vmcnt(4)" ::: "memory");  // T0 landed
  __builtin_amdgcn_s_barrier();
  __builtin_amdgcn_sched_barrier(0);

  // ---- main: t = 0..59 (20 x 3), then tail t = 60,61,62,63 ----
#pragma unroll 1
  for (int tt = 0; tt < 60; tt += 3) {
    TILE_BODY(tt + 0, 0, 2, true, 4);
    TILE_BODY(tt + 1, 1, 0, true, 4);
    TILE_BODY(tt + 2, 2, 1, true, 4);
  }
  TILE_BODY(60, 0, 2, true, 4);   // stages T62 -> buf2
  TILE_BODY(61, 1, 0, true, 4);   // stages T63 -> buf0 (buf0 last read t=60)
  TILE_BODY(62, 2, 0, false, 0);  // no stage; drain T63
  {                               // t = 63: bare compute (buf0)
    const unsigned char* Ab = ldsA;
    const unsigned char* Bb = ldsB;
    i32x4 af[8], bf[4];
#pragma unroll
    for (int ni = 0; ni < 4; ++ni)
      bf[ni] = *(const i32x4*)(Bb + bro + ni * 1024);
#pragma unroll
    for (int m = 0; m < 8; ++m)
      af[m] = *(const i32x4*)(Ab + aro + m * 1024);
#pragma unroll
    for (int m = 0; m < 8; ++m)
#pragma unroll
      for (int ni = 0; ni < 4; ++ni)
        acc[m][ni] = MFMA_I8(af[m], bf[ni], acc[m][ni], 0, 0, 0);
  }

  // ---- epilogue: out = i32acc * steps[m] (proven) ----
  const int cn = lane & 15;
  const int cm = (lane >> 4) * 4;
  float stp[8][4];
#pragma unroll
  for (int mi = 0; mi < 8; ++mi)
#pragma unroll
    for (int r = 0; r < 4; ++r)
      stp[mi][r] = steps[bm + wm + mi * 16 + cm + r];
#pragma unroll
  for (int mi = 0; mi < 8; ++mi) {
#pragma unroll
    for (int ni = 0; ni < 4; ++ni) {
#pragma unroll
      for (int r = 0; r < 4; ++r) {
        const int m = bm + wm + mi * 16 + cm + r;
        const int n = bn + wn + ni * 16 + cn;
        C[(size_t)m * NDIM + n] = (float)acc[mi][ni][r] * stp[mi][r];
      }
    }
  }
}

// ---------------------------------------------------------------------------
extern "C" void kernel_launch(void* const* d_in, const int* in_sizes, int n_in,
                              void* d_out, int out_size, void* d_ws,
                              size_t ws_size, hipStream_t stream) {
  const float* x = (const float*)d_in[0];
  const float* w = (const float*)d_in[1];
  float* out = (float*)d_out;

  const int K = 4096;
  const int N = 4096;
  const int NW = in_sizes[1];      // 4096*4096

  char* ws = (char*)d_ws;
  double* d_sum = (double*)ws;                               // 8 B
  float* steps = (float*)(ws + 256);                         // M floats (32 KB)
  signed char* qb = (signed char*)(ws + 65536);              // N*K i8 (16.8 MB)
  signed char* xq = qb + (size_t)N * K;                      // M*K i8 (33.6 MB)

  hipMemsetAsync(d_sum, 0, sizeof(double), stream);
  prep_kernel<<<M_ROWS + ABS_BLOCKS, 256, 0, stream>>>(
      (const float4*)x, xq, steps, (const float4*)w, NW / 4, d_sum);
  quant_kernel<<<2048, 256, 0, stream>>>((const float4*)w, d_sum, (int*)qb,
                                         NW / 4, 1.0 / NW);
  dim3 grid(N / 256, M_ROWS / 256);
  gemm_i8_3buf<<<grid, 512, 0, stream>>>(xq, qb, steps, out);
}